// Round 5
// baseline (453.648 us; speedup 1.0000x reference)
//
#include <hip/hip_runtime.h>

// Cumulative average along last axis: y[..., t] = cumsum(x)[..., t] / (t+1)
// x: fp32, shape (8, 512, 16384) -> 4096 independent rows of T=16384.
//
// v5: wave-autonomous streaming. ONE wave per row; no barriers, no LDS,
// no inter-wave coupling of any kind (v2-v4 all pinned at ~170us with
// block-phase coupling: burst-load -> vmcnt(0) -> scan -> barrier -> burst
// -> store left the VMEM pipe idle between phases).
//   - row = 64 tiles of 256 elems (lane-major float4 -> coalesced 1KiB/instr)
//   - processed as 16 groups of 4 tiles; 3 named buffers (b0/b1/b2) give a
//     distance-2 software pipeline: group g computes while g+1,g+2 load.
//     All buffer refs are compile-time (runtime-indexed arrays -> scratch).
//   - per group: 4 independent wave-64 shfl scans interleaved (DS-pipe ILP),
//     register carry across tiles, lane-63 broadcast for tile totals.
//   - nontemporal float4 stores (keep the ~L3-sized input resident).
//   - divide via v_rcp_f32 * (rel err ~2^-22 << 2e-3 tolerance).

#define ROW_T   16384
#define TILE_E  256                  // 64 lanes * float4
#define NTILES  (ROW_T / TILE_E)     // 64 tiles per row
#define GRP     4                    // tiles per group
#define NGRP    (NTILES / GRP)       // 16 groups
#define WPB     4                    // independent waves per block
#define THREADS (WPB * 64)

typedef float f32x4 __attribute__((ext_vector_type(4)));

#define LOADG(buf, g)                                                        \
    do {                                                                     \
        _Pragma("unroll")                                                    \
        for (int k = 0; k < GRP; ++k)                                        \
            buf[k] = *reinterpret_cast<const f32x4*>(px + ((g) * GRP + k) * TILE_E); \
    } while (0)

__global__ __launch_bounds__(THREADS, 4)
void cumavg_kernel(const float* __restrict__ x, float* __restrict__ y) {
    const int  lane = threadIdx.x & 63;
    const int  wave = threadIdx.x >> 6;
    const int  row  = blockIdx.x * WPB + wave;
    const long base = (long)row * ROW_T;

    const float* px = x + base + lane * 4;
    float*       py = y + base + lane * 4;

    const float flane = (float)(lane * 4);   // per-lane part of the divisor

    float carry = 0.0f;

    // Process one group of 4 tiles held in v[]; g is always a literal.
    auto proc = [&](const int g, f32x4 (&v)[GRP]) __attribute__((always_inline)) {
        float ts[GRP], inc[GRP];
        #pragma unroll
        for (int k = 0; k < GRP; ++k) {
            ts[k]  = (v[k].x + v[k].y) + (v[k].z + v[k].w);
            inc[k] = ts[k];
        }
        // 4 independent inclusive scans, interleaved for DS-pipe ILP
        #pragma unroll
        for (int d = 1; d < 64; d <<= 1) {
            #pragma unroll
            for (int k = 0; k < GRP; ++k) {
                float n = __shfl_up(inc[k], d, 64);
                if (lane >= d) inc[k] += n;
            }
        }
        // Tile totals (broadcast lane 63), issued together
        float tot[GRP];
        #pragma unroll
        for (int k = 0; k < GRP; ++k) tot[k] = __shfl(inc[k], 63, 64);

        #pragma unroll
        for (int k = 0; k < GRP; ++k) {
            const int cbase = ((g) * GRP + k) * TILE_E;   // compile-time
            float ex = carry + (inc[k] - ts[k]);          // excl. prefix, 1st elem

            float s0 = ex + v[k].x;
            float s1 = s0 + v[k].y;
            float s2 = s1 + v[k].z;
            float s3 = s2 + v[k].w;

            f32x4 o;
            o.x = s0 * __builtin_amdgcn_rcpf(flane + (float)(cbase + 1));
            o.y = s1 * __builtin_amdgcn_rcpf(flane + (float)(cbase + 2));
            o.z = s2 * __builtin_amdgcn_rcpf(flane + (float)(cbase + 3));
            o.w = s3 * __builtin_amdgcn_rcpf(flane + (float)(cbase + 4));

            __builtin_nontemporal_store(o, reinterpret_cast<f32x4*>(py + cbase));

            carry += tot[k];
        }
    };

    f32x4 b0[GRP], b1[GRP], b2[GRP];
    LOADG(b0, 0); LOADG(b1, 1); LOADG(b2, 2);

    // 16 groups, buffer g%3, refill with g+3 right after use (distance-2 pipe)
    proc( 0, b0); LOADG(b0,  3);
    proc( 1, b1); LOADG(b1,  4);
    proc( 2, b2); LOADG(b2,  5);
    proc( 3, b0); LOADG(b0,  6);
    proc( 4, b1); LOADG(b1,  7);
    proc( 5, b2); LOADG(b2,  8);
    proc( 6, b0); LOADG(b0,  9);
    proc( 7, b1); LOADG(b1, 10);
    proc( 8, b2); LOADG(b2, 11);
    proc( 9, b0); LOADG(b0, 12);
    proc(10, b1); LOADG(b1, 13);
    proc(11, b2); LOADG(b2, 14);
    proc(12, b0); LOADG(b0, 15);
    proc(13, b1);
    proc(14, b2);
    proc(15, b0);
}

extern "C" void kernel_launch(void* const* d_in, const int* in_sizes, int n_in,
                              void* d_out, int out_size, void* d_ws, size_t ws_size,
                              hipStream_t stream) {
    const float* x = (const float*)d_in[0];
    float*       y = (float*)d_out;
    const int rows = in_sizes[0] / ROW_T;   // 8*512 = 4096
    hipLaunchKernelGGL(cumavg_kernel, dim3(rows / WPB), dim3(THREADS), 0, stream, x, y);
}